// Round 1
// baseline (1621.167 us; speedup 1.0000x reference)
//
#include <hip/hip_runtime.h>

#define NU 100000
#define NI 50000
#define NB 1000
#define NN 151000          // total nodes
#define NE 4800000
#define DD 64
#define KDIM 448

// ---------------- histogram: count edges per row ----------------
__global__ __launch_bounds__(256) void hist_kernel(const int* __restrict__ row,
                                                   int* __restrict__ cnt) {
  int e = blockIdx.x * 256 + threadIdx.x;
  if (e < NE) atomicAdd(&cnt[row[e]], 1);
}

// ---------------- hierarchical exclusive scan over NN counts ----------------
// scan1: 148 blocks x 256 threads, 4 elems/thread (1024/block).
__global__ __launch_bounds__(256) void scan1_kernel(int* __restrict__ data,
                                                    int* __restrict__ bsum, int n) {
  __shared__ int sh[256];
  int tid = threadIdx.x;
  int base = blockIdx.x * 1024 + tid * 4;
  int v[4];
#pragma unroll
  for (int j = 0; j < 4; ++j) v[j] = (base + j < n) ? data[base + j] : 0;
  int tsum = v[0] + v[1] + v[2] + v[3];
  sh[tid] = tsum;
  __syncthreads();
#pragma unroll
  for (int off = 1; off < 256; off <<= 1) {
    int t = (tid >= off) ? sh[tid - off] : 0;
    __syncthreads();
    sh[tid] += t;
    __syncthreads();
  }
  int incl = sh[tid];
  int excl = incl - tsum;
  if (tid == 255) bsum[blockIdx.x] = incl;
  int run = excl;
#pragma unroll
  for (int j = 0; j < 4; ++j) {
    int nv = run;
    run += v[j];
    if (base + j < n) data[base + j] = nv;
  }
}

// scan2: single block scans the <=256 block sums (exclusive, in place), writes total.
__global__ __launch_bounds__(256) void scan2_kernel(int* __restrict__ bsum, int nb,
                                                    int* __restrict__ total_out) {
  __shared__ int sh[256];
  int tid = threadIdx.x;
  int v = (tid < nb) ? bsum[tid] : 0;
  sh[tid] = v;
  __syncthreads();
#pragma unroll
  for (int off = 1; off < 256; off <<= 1) {
    int t = (tid >= off) ? sh[tid - off] : 0;
    __syncthreads();
    sh[tid] += t;
    __syncthreads();
  }
  if (tid < nb) bsum[tid] = sh[tid] - v;  // exclusive
  if (tid == 255) *total_out = sh[255];
}

// scan3: add scanned block sums back.
__global__ __launch_bounds__(256) void scan3_kernel(int* __restrict__ data,
                                                    const int* __restrict__ bsum, int n) {
  int add = bsum[blockIdx.x];
  int base = blockIdx.x * 1024 + threadIdx.x * 4;
#pragma unroll
  for (int j = 0; j < 4; ++j)
    if (base + j < n) data[base + j] += add;
}

// ---------------- scatter edges into CSR ----------------
__global__ __launch_bounds__(256) void scatter_kernel(
    const int* __restrict__ erow, const int* __restrict__ ecol,
    const float* __restrict__ eval, const int* __restrict__ rp,
    int* __restrict__ fill, int* __restrict__ scol, float* __restrict__ sval) {
  int e = blockIdx.x * 256 + threadIdx.x;
  if (e >= NE) return;
  int r = erow[e];
  int p = rp[r] + atomicAdd(&fill[r], 1);
  scol[p] = ecol[e];
  sval[p] = eval[e];
}

// ---------------- fusion GEMM: [NI x 448] @ [448 x 64]^T(ish) + bias + leaky ----------------
// out[i][d] = leaky( sum_k combined[i][k] * W[d][k] + b[d] )
__global__ __launch_bounds__(256) void fusion_kernel(
    const float* __restrict__ id_emb, const float* __restrict__ content,
    const float* __restrict__ W, const float* __restrict__ bias,
    float* __restrict__ ego) {
  __shared__ float As[16][68];  // [k][item], pad 68 -> 16B aligned rows
  __shared__ float Ws[16][68];  // [k][dim]
  int tid = threadIdx.x;
  int tx = tid & 15;   // dim group: d0 = tx*4
  int ty = tid >> 4;   // item group: i0 = ty*4
  int itemBase = blockIdx.x * 64;
  float acc[4][4] = {};

  int it = tid >> 2;        // 0..63 (item offset for A, dim for W)
  int kq = (tid & 3) * 4;   // 0,4,8,12

  for (int kb = 0; kb < KDIM; kb += 16) {
    int k = kb + kq;
    int item = itemBase + it;
    int itemc = item < NI ? item : NI - 1;
    float4 a;
    if (k < 64)
      a = *(const float4*)&id_emb[(size_t)itemc * 64 + k];
    else
      a = *(const float4*)&content[(size_t)itemc * 384 + (k - 64)];
    As[kq + 0][it] = a.x; As[kq + 1][it] = a.y; As[kq + 2][it] = a.z; As[kq + 3][it] = a.w;
    float4 w = *(const float4*)&W[(size_t)it * KDIM + k];
    Ws[kq + 0][it] = w.x; Ws[kq + 1][it] = w.y; Ws[kq + 2][it] = w.z; Ws[kq + 3][it] = w.w;
    __syncthreads();
#pragma unroll
    for (int kk = 0; kk < 16; ++kk) {
      float4 af = *(float4*)&As[kk][ty * 4];
      float4 wf = *(float4*)&Ws[kk][tx * 4];
      float av[4] = {af.x, af.y, af.z, af.w};
      float wv[4] = {wf.x, wf.y, wf.z, wf.w};
#pragma unroll
      for (int m = 0; m < 4; ++m)
#pragma unroll
        for (int n = 0; n < 4; ++n) acc[m][n] += av[m] * wv[n];
    }
    __syncthreads();
  }

  int d0 = tx * 4;
  float4 bb = *(const float4*)&bias[d0];
  float bv[4] = {bb.x, bb.y, bb.z, bb.w};
#pragma unroll
  for (int m = 0; m < 4; ++m) {
    int item = itemBase + ty * 4 + m;
    if (item >= NI) continue;
    float4 o;
    float t;
    t = acc[m][0] + bv[0]; o.x = t >= 0.f ? t : 0.01f * t;
    t = acc[m][1] + bv[1]; o.y = t >= 0.f ? t : 0.01f * t;
    t = acc[m][2] + bv[2]; o.z = t >= 0.f ? t : 0.01f * t;
    t = acc[m][3] + bv[3]; o.w = t >= 0.f ? t : 0.01f * t;
    *(float4*)&ego[(size_t)(NU + item) * 64 + d0] = o;
  }
}

// ---------------- SpMM: one wave per row ----------------
template <bool FINAL>
__global__ __launch_bounds__(256) void spmm_kernel(
    const int* __restrict__ rp, const int* __restrict__ cols,
    const float* __restrict__ vals, const float* __restrict__ x,
    float* __restrict__ y, float* __restrict__ acc) {
  int wid = blockIdx.x * 4 + (threadIdx.x >> 6);
  int lane = threadIdx.x & 63;
  if (wid >= NN) return;
  int beg = rp[wid], end = rp[wid + 1];
  float s = 0.f;
  for (int j0 = beg; j0 < end; j0 += 64) {
    int jj = j0 + lane;
    int c = 0;
    float v = 0.f;
    if (jj < end) { c = cols[jj]; v = vals[jj]; }
    int cnt = min(64, end - j0);
    for (int i = 0; i < cnt; ++i) {
      int ci = __shfl(c, i);
      float vi = __shfl(v, i);
      s += vi * x[(size_t)ci * 64 + lane];
    }
  }
  size_t o = (size_t)wid * 64 + lane;
  if (FINAL) {
    acc[o] = (acc[o] + s) * 0.25f;
  } else {
    y[o] = s;
    acc[o] += s;
  }
}

extern "C" void kernel_launch(void* const* d_in, const int* in_sizes, int n_in,
                              void* d_out, int out_size, void* d_ws, size_t ws_size,
                              hipStream_t stream) {
  const int*   edge_row = (const int*)d_in[0];
  const int*   edge_col = (const int*)d_in[1];
  const float* edge_val = (const float*)d_in[2];
  const float* user_emb = (const float*)d_in[3];
  const float* item_id  = (const float*)d_in[4];
  const float* brand    = (const float*)d_in[5];
  const float* content  = (const float*)d_in[6];
  const float* W        = (const float*)d_in[7];
  const float* bias     = (const float*)d_in[8];
  float* out = (float*)d_out;

  char* ws = (char*)d_ws;
  size_t off = 0;
  auto alloc = [&](size_t bytes) -> void* {
    void* p = ws + off;
    off += (bytes + 255) & ~(size_t)255;
    return p;
  };
  float* ego0 = (float*)alloc((size_t)NN * 64 * 4);
  float* ego1 = (float*)alloc((size_t)NN * 64 * 4);
  int*   rp   = (int*)alloc((size_t)(NN + 1) * 4);
  int*   fill = (int*)alloc((size_t)NN * 4);
  int*   bsum = (int*)alloc(256 * 4);
  int*   scol = (int*)alloc((size_t)NE * 4);
  float* sval = (float*)alloc((size_t)NE * 4);
  if (off > ws_size) return;  // insufficient workspace -> fail visibly

  // --- build CSR ---
  hipMemsetAsync(rp, 0, (size_t)(NN + 1) * 4, stream);
  hipMemsetAsync(fill, 0, (size_t)NN * 4, stream);
  hist_kernel<<<(NE + 255) / 256, 256, 0, stream>>>(edge_row, rp);
  const int nScanBlocks = (NN + 1023) / 1024;  // 148 (<=256)
  scan1_kernel<<<nScanBlocks, 256, 0, stream>>>(rp, bsum, NN);
  scan2_kernel<<<1, 256, 0, stream>>>(bsum, nScanBlocks, &rp[NN]);
  scan3_kernel<<<nScanBlocks, 256, 0, stream>>>(rp, bsum, NN);
  scatter_kernel<<<(NE + 255) / 256, 256, 0, stream>>>(edge_row, edge_col, edge_val,
                                                       rp, fill, scol, sval);

  // --- assemble ego0 = [user_emb | fused_item | brand_emb] ---
  hipMemcpyAsync(ego0, user_emb, (size_t)NU * 64 * 4, hipMemcpyDeviceToDevice, stream);
  hipMemcpyAsync(ego0 + (size_t)(NU + NI) * 64, brand, (size_t)NB * 64 * 4,
                 hipMemcpyDeviceToDevice, stream);
  fusion_kernel<<<(NI + 63) / 64, 256, 0, stream>>>(item_id, content, W, bias, ego0);

  // acc init = ego0 (acc lives in d_out[0 : NN*64])
  hipMemcpyAsync(out, ego0, (size_t)NN * 64 * 4, hipMemcpyDeviceToDevice, stream);

  // --- 3 propagation layers ---
  const int spmmGrid = (NN + 3) / 4;
  spmm_kernel<false><<<spmmGrid, 256, 0, stream>>>(rp, scol, sval, ego0, ego1, out);
  spmm_kernel<false><<<spmmGrid, 256, 0, stream>>>(rp, scol, sval, ego1, ego0, out);
  spmm_kernel<true><<<spmmGrid, 256, 0, stream>>>(rp, scol, sval, ego0, ego1, out);

  // --- passthrough outputs ---
  hipMemcpyAsync(out + (size_t)NN * 64, user_emb, (size_t)NU * 64 * 4,
                 hipMemcpyDeviceToDevice, stream);
  hipMemcpyAsync(out + (size_t)NN * 64 + (size_t)NU * 64, item_id,
                 (size_t)NI * 64 * 4, hipMemcpyDeviceToDevice, stream);
}

// Round 2
// 1341.845 us; speedup vs baseline: 1.2082x; 1.2082x over previous
//
#include <hip/hip_runtime.h>
#include <hip/hip_fp16.h>

#define NU 100000
#define NI 50000
#define NB 1000
#define NN 151000          // total nodes
#define NE 4800000
#define KDIM 448

#define BROW_BITS 7
#define BROWS 128                       // rows per bucket
#define NBK ((NN + BROWS - 1) / BROWS)  // 1180 buckets

// ================= Phase A: bucket histogram (LDS-aggregated) =================
#define HIST_EPT 16
__global__ __launch_bounds__(256) void bucket_hist(const int* __restrict__ erow,
                                                   int* __restrict__ bcnt) {
  __shared__ int lh[NBK];
  for (int i = threadIdx.x; i < NBK; i += 256) lh[i] = 0;
  __syncthreads();
  int base = blockIdx.x * (256 * HIST_EPT) + threadIdx.x;
#pragma unroll
  for (int j = 0; j < HIST_EPT; ++j) {
    int e = base + j * 256;
    if (e < NE) atomicAdd(&lh[erow[e] >> BROW_BITS], 1);
  }
  __syncthreads();
  for (int i = threadIdx.x; i < NBK; i += 256) {
    int c = lh[i];
    if (c) atomicAdd(&bcnt[i], c);
  }
}

// ================= Phase B: scan 1180 bucket counts (single block) =================
__global__ __launch_bounds__(256) void bucket_scan(const int* __restrict__ bcnt,
                                                   int* __restrict__ bstart,
                                                   int* __restrict__ rp) {
  __shared__ int sh[256];
  int tid = threadIdx.x;
  int v[5];
  int s = 0;
#pragma unroll
  for (int j = 0; j < 5; ++j) {
    int i = tid * 5 + j;
    v[j] = (i < NBK) ? bcnt[i] : 0;
    s += v[j];
  }
  sh[tid] = s;
  __syncthreads();
  for (int off = 1; off < 256; off <<= 1) {
    int t = (tid >= off) ? sh[tid - off] : 0;
    __syncthreads();
    sh[tid] += t;
    __syncthreads();
  }
  int run = sh[tid] - s;  // exclusive
#pragma unroll
  for (int j = 0; j < 5; ++j) {
    int i = tid * 5 + j;
    if (i < NBK) bstart[i] = run;
    run += v[j];
  }
  if (tid == 255) {
    bstart[NBK] = NE;
    rp[NN] = NE;
  }
}

// ================= Phase C: scatter edges into bucket order =================
// key packs (row&127)<<18 | col  (col < 151000 < 2^18)
#define SC_EPT 8
__global__ __launch_bounds__(256) void bucket_scatter(
    const int* __restrict__ erow, const int* __restrict__ ecol,
    const float* __restrict__ eval, const int* __restrict__ bstart,
    int* __restrict__ gfill, int* __restrict__ bkey, float* __restrict__ bval) {
  __shared__ int lcnt[NBK];
  __shared__ int lbase[NBK];
  for (int i = threadIdx.x; i < NBK; i += 256) lcnt[i] = 0;
  __syncthreads();
  int base = blockIdx.x * (256 * SC_EPT) + threadIdx.x;
  int key[SC_EPT], bk[SC_EPT], rank[SC_EPT];
  float vv[SC_EPT];
#pragma unroll
  for (int j = 0; j < SC_EPT; ++j) {
    int e = base + j * 256;
    if (e < NE) {
      int r = erow[e];
      int c = ecol[e];
      vv[j] = eval[e];
      bk[j] = r >> BROW_BITS;
      key[j] = ((r & (BROWS - 1)) << 18) | c;
      rank[j] = atomicAdd(&lcnt[bk[j]], 1);
    } else {
      bk[j] = -1;
    }
  }
  __syncthreads();
  for (int i = threadIdx.x; i < NBK; i += 256) {
    int c = lcnt[i];
    lbase[i] = c ? atomicAdd(&gfill[i], c) : 0;
  }
  __syncthreads();
#pragma unroll
  for (int j = 0; j < SC_EPT; ++j) {
    if (bk[j] >= 0) {
      int p = bstart[bk[j]] + lbase[bk[j]] + rank[j];
      bkey[p] = key[j];
      bval[p] = vv[j];
    }
  }
}

// ================= Phase D: per-bucket CSR finalize + rp =================
__global__ __launch_bounds__(256) void csr_finalize(
    const int* __restrict__ bstart, const int* __restrict__ bkey,
    const float* __restrict__ bval, int* __restrict__ rp,
    int* __restrict__ scol, float* __restrict__ sval) {
  __shared__ int rcnt[BROWS];
  __shared__ int rex[BROWS];
  __shared__ int ss[BROWS];
  int b = blockIdx.x;
  int s0 = bstart[b], s1 = bstart[b + 1];
  int tid = threadIdx.x;
  if (tid < BROWS) rcnt[tid] = 0;
  __syncthreads();
  for (int j = s0 + tid; j < s1; j += 256) atomicAdd(&rcnt[bkey[j] >> 18], 1);
  __syncthreads();
  int v = (tid < BROWS) ? rcnt[tid] : 0;
  if (tid < BROWS) ss[tid] = v;
  __syncthreads();
  for (int off = 1; off < BROWS; off <<= 1) {
    int t = 0;
    if (tid < BROWS && tid >= off) t = ss[tid - off];
    __syncthreads();
    if (tid < BROWS) ss[tid] += t;
    __syncthreads();
  }
  if (tid < BROWS) {
    rex[tid] = ss[tid] - v;  // exclusive within bucket
    int row = b * BROWS + tid;
    if (row < NN) rp[row] = s0 + rex[tid];
    rcnt[tid] = 0;
  }
  __syncthreads();
  for (int j = s0 + tid; j < s1; j += 256) {
    int k = bkey[j];
    int r = k >> 18;
    int c = k & 0x3FFFF;
    int rk = atomicAdd(&rcnt[r], 1);
    int p = s0 + rex[r] + rk;
    scol[p] = c;
    sval[p] = bval[j];
  }
}

// ================= fusion GEMM: [NI x 448] @ W^T + bias + leaky =================
__global__ __launch_bounds__(256) void fusion_kernel(
    const float* __restrict__ id_emb, const float* __restrict__ content,
    const float* __restrict__ W, const float* __restrict__ bias,
    float* __restrict__ ego) {
  __shared__ float As[16][68];
  __shared__ float Ws[16][68];
  int tid = threadIdx.x;
  int tx = tid & 15;
  int ty = tid >> 4;
  int itemBase = blockIdx.x * 64;
  float acc[4][4] = {};

  int it = tid >> 2;
  int kq = (tid & 3) * 4;

  for (int kb = 0; kb < KDIM; kb += 16) {
    int k = kb + kq;
    int item = itemBase + it;
    int itemc = item < NI ? item : NI - 1;
    float4 a;
    if (k < 64)
      a = *(const float4*)&id_emb[(size_t)itemc * 64 + k];
    else
      a = *(const float4*)&content[(size_t)itemc * 384 + (k - 64)];
    As[kq + 0][it] = a.x; As[kq + 1][it] = a.y; As[kq + 2][it] = a.z; As[kq + 3][it] = a.w;
    float4 w = *(const float4*)&W[(size_t)it * KDIM + k];
    Ws[kq + 0][it] = w.x; Ws[kq + 1][it] = w.y; Ws[kq + 2][it] = w.z; Ws[kq + 3][it] = w.w;
    __syncthreads();
#pragma unroll
    for (int kk = 0; kk < 16; ++kk) {
      float4 af = *(float4*)&As[kk][ty * 4];
      float4 wf = *(float4*)&Ws[kk][tx * 4];
      float av[4] = {af.x, af.y, af.z, af.w};
      float wv[4] = {wf.x, wf.y, wf.z, wf.w};
#pragma unroll
      for (int m = 0; m < 4; ++m)
#pragma unroll
        for (int n = 0; n < 4; ++n) acc[m][n] += av[m] * wv[n];
    }
    __syncthreads();
  }

  int d0 = tx * 4;
  float4 bb = *(const float4*)&bias[d0];
  float bv[4] = {bb.x, bb.y, bb.z, bb.w};
#pragma unroll
  for (int m = 0; m < 4; ++m) {
    int item = itemBase + ty * 4 + m;
    if (item >= NI) continue;
    float4 o;
    float t;
    t = acc[m][0] + bv[0]; o.x = t >= 0.f ? t : 0.01f * t;
    t = acc[m][1] + bv[1]; o.y = t >= 0.f ? t : 0.01f * t;
    t = acc[m][2] + bv[2]; o.z = t >= 0.f ? t : 0.01f * t;
    t = acc[m][3] + bv[3]; o.w = t >= 0.f ? t : 0.01f * t;
    *(float4*)&ego[(size_t)(NU + item) * 64 + d0] = o;
  }
}

// ================= fp32 -> fp16 convert =================
__global__ __launch_bounds__(256) void f2h_kernel(const float* __restrict__ x,
                                                  __half* __restrict__ y, int n) {
  int idx = (blockIdx.x * 256 + threadIdx.x) * 4;
  if (idx < n) {
    float4 f = *(const float4*)&x[idx];
    __half2 h0 = __floats2half2_rn(f.x, f.y);
    __half2 h1 = __floats2half2_rn(f.z, f.w);
    *(__half2*)&y[idx] = h0;
    *(__half2*)&y[idx + 2] = h1;
  }
}

// ================= SpMM: one wave per row, fp16 gather =================
template <bool FINAL>
__global__ __launch_bounds__(256) void spmm_kernel(
    const int* __restrict__ rp, const int* __restrict__ cols,
    const float* __restrict__ vals, const __half* __restrict__ x,
    __half* __restrict__ y, float* __restrict__ acc) {
  int wid = blockIdx.x * 4 + (threadIdx.x >> 6);
  int lane = threadIdx.x & 63;
  if (wid >= NN) return;
  int beg = rp[wid], end = rp[wid + 1];
  float s = 0.f;
  for (int j0 = beg; j0 < end; j0 += 64) {
    int jj = j0 + lane;
    int c = 0;
    float v = 0.f;
    if (jj < end) { c = cols[jj]; v = vals[jj]; }
    int cnt = min(64, end - j0);
    for (int i = 0; i < cnt; ++i) {
      int ci = __shfl(c, i);
      float vi = __shfl(v, i);
      s += vi * __half2float(x[(size_t)ci * 64 + lane]);
    }
  }
  size_t o = (size_t)wid * 64 + lane;
  if (FINAL) {
    acc[o] = (acc[o] + s) * 0.25f;
  } else {
    y[o] = __float2half(s);
    acc[o] += s;
  }
}

extern "C" void kernel_launch(void* const* d_in, const int* in_sizes, int n_in,
                              void* d_out, int out_size, void* d_ws, size_t ws_size,
                              hipStream_t stream) {
  const int*   edge_row = (const int*)d_in[0];
  const int*   edge_col = (const int*)d_in[1];
  const float* edge_val = (const float*)d_in[2];
  const float* user_emb = (const float*)d_in[3];
  const float* item_id  = (const float*)d_in[4];
  const float* brand    = (const float*)d_in[5];
  const float* content  = (const float*)d_in[6];
  const float* W        = (const float*)d_in[7];
  const float* bias     = (const float*)d_in[8];
  float* out = (float*)d_out;

  char* ws = (char*)d_ws;
  size_t off = 0;
  auto alloc = [&](size_t bytes) -> void* {
    void* p = ws + off;
    off += (bytes + 255) & ~(size_t)255;
    return p;
  };
  const size_t halfBufBytes = (size_t)NN * 64 * 2;  // 19.33 MB
  const size_t slotBytes = halfBufBytes > (size_t)NE * 4 ? halfBufBytes : (size_t)NE * 4;

  float* ego0f = (float*)alloc((size_t)NN * 64 * 4);  // fp32 ego (acc seed)
  void*  slotA = alloc(slotBytes);   // bkey during sort, xh0 during spmm
  void*  slotB = alloc(slotBytes);   // bval during sort, xh1 during spmm
  int*   rp    = (int*)alloc((size_t)(NN + 1) * 4);
  int*   bcnt  = (int*)alloc((NBK + 1) * 4);
  int*   bstart= (int*)alloc((NBK + 1) * 4);
  int*   gfill = (int*)alloc((NBK + 1) * 4);
  int*   scol  = (int*)alloc((size_t)NE * 4);
  float* sval  = (float*)alloc((size_t)NE * 4);
  if (off > ws_size) return;

  int*   bkey = (int*)slotA;
  float* bval = (float*)slotB;
  __half* xh0 = (__half*)slotA;
  __half* xh1 = (__half*)slotB;

  // --- build CSR via two-level counting sort ---
  hipMemsetAsync(bcnt, 0, (NBK + 1) * 4, stream);
  hipMemsetAsync(gfill, 0, (NBK + 1) * 4, stream);
  const int histBlocks = (NE + 256 * HIST_EPT - 1) / (256 * HIST_EPT);
  bucket_hist<<<histBlocks, 256, 0, stream>>>(edge_row, bcnt);
  bucket_scan<<<1, 256, 0, stream>>>(bcnt, bstart, rp);
  const int scBlocks = (NE + 256 * SC_EPT - 1) / (256 * SC_EPT);
  bucket_scatter<<<scBlocks, 256, 0, stream>>>(edge_row, edge_col, edge_val,
                                               bstart, gfill, bkey, bval);
  csr_finalize<<<NBK, 256, 0, stream>>>(bstart, bkey, bval, rp, scol, sval);

  // --- assemble ego0f = [user_emb | fused_item | brand_emb] ---
  hipMemcpyAsync(ego0f, user_emb, (size_t)NU * 64 * 4, hipMemcpyDeviceToDevice, stream);
  hipMemcpyAsync(ego0f + (size_t)(NU + NI) * 64, brand, (size_t)NB * 64 * 4,
                 hipMemcpyDeviceToDevice, stream);
  fusion_kernel<<<(NI + 63) / 64, 256, 0, stream>>>(item_id, content, W, bias, ego0f);

  // acc seed (out = ego0f), half conversion AFTER csr_finalize frees slotA
  hipMemcpyAsync(out, ego0f, (size_t)NN * 64 * 4, hipMemcpyDeviceToDevice, stream);
  const int nEl = NN * 64;
  f2h_kernel<<<(nEl / 4 + 255) / 256, 256, 0, stream>>>(ego0f, xh0, nEl);

  // --- 3 propagation layers ---
  const int spmmGrid = (NN + 3) / 4;
  spmm_kernel<false><<<spmmGrid, 256, 0, stream>>>(rp, scol, sval, xh0, xh1, out);
  spmm_kernel<false><<<spmmGrid, 256, 0, stream>>>(rp, scol, sval, xh1, xh0, out);
  spmm_kernel<true><<<spmmGrid, 256, 0, stream>>>(rp, scol, sval, xh0, xh1, out);

  // --- passthrough outputs ---
  hipMemcpyAsync(out + (size_t)NN * 64, user_emb, (size_t)NU * 64 * 4,
                 hipMemcpyDeviceToDevice, stream);
  hipMemcpyAsync(out + (size_t)NN * 64 + (size_t)NU * 64, item_id,
                 (size_t)NI * 64 * 4, hipMemcpyDeviceToDevice, stream);
}

// Round 3
// 880.332 us; speedup vs baseline: 1.8415x; 1.5242x over previous
//
#include <hip/hip_runtime.h>
#include <hip/hip_fp16.h>

#define NU 100000
#define NI 50000
#define NB 1000
#define NN 151000          // total nodes
#define NE 4800000
#define KDIM 448

#define BROW_BITS 7
#define BROWS 128                       // rows per bucket
#define NBK ((NN + BROWS - 1) / BROWS)  // 1180 buckets

// ================= Phase A: bucket histogram (LDS-aggregated) =================
#define HIST_EPT 16
__global__ __launch_bounds__(256) void bucket_hist(const int* __restrict__ erow,
                                                   int* __restrict__ bcnt) {
  __shared__ int lh[NBK];
  for (int i = threadIdx.x; i < NBK; i += 256) lh[i] = 0;
  __syncthreads();
  int base = blockIdx.x * (256 * HIST_EPT) + threadIdx.x;
#pragma unroll
  for (int j = 0; j < HIST_EPT; ++j) {
    int e = base + j * 256;
    if (e < NE) atomicAdd(&lh[erow[e] >> BROW_BITS], 1);
  }
  __syncthreads();
  for (int i = threadIdx.x; i < NBK; i += 256) {
    int c = lh[i];
    if (c) atomicAdd(&bcnt[i], c);
  }
}

// ================= Phase B: scan 1180 bucket counts (single block) =================
__global__ __launch_bounds__(256) void bucket_scan(const int* __restrict__ bcnt,
                                                   int* __restrict__ bstart,
                                                   int* __restrict__ rp) {
  __shared__ int sh[256];
  int tid = threadIdx.x;
  int v[5];
  int s = 0;
#pragma unroll
  for (int j = 0; j < 5; ++j) {
    int i = tid * 5 + j;
    v[j] = (i < NBK) ? bcnt[i] : 0;
    s += v[j];
  }
  sh[tid] = s;
  __syncthreads();
  for (int off = 1; off < 256; off <<= 1) {
    int t = (tid >= off) ? sh[tid - off] : 0;
    __syncthreads();
    sh[tid] += t;
    __syncthreads();
  }
  int run = sh[tid] - s;  // exclusive
#pragma unroll
  for (int j = 0; j < 5; ++j) {
    int i = tid * 5 + j;
    if (i < NBK) bstart[i] = run;
    run += v[j];
  }
  if (tid == 255) {
    bstart[NBK] = NE;
    rp[NN] = NE;
  }
}

// ================= Phase C: scatter edges into bucket order =================
// key packs (row&127)<<18 | col  (col < 151000 < 2^18)
#define SC_EPT 8
__global__ __launch_bounds__(256) void bucket_scatter(
    const int* __restrict__ erow, const int* __restrict__ ecol,
    const float* __restrict__ eval, const int* __restrict__ bstart,
    int* __restrict__ gfill, int* __restrict__ bkey, float* __restrict__ bval) {
  __shared__ int lcnt[NBK];
  __shared__ int lbase[NBK];
  for (int i = threadIdx.x; i < NBK; i += 256) lcnt[i] = 0;
  __syncthreads();
  int base = blockIdx.x * (256 * SC_EPT) + threadIdx.x;
  int key[SC_EPT], bk[SC_EPT], rank[SC_EPT];
  float vv[SC_EPT];
#pragma unroll
  for (int j = 0; j < SC_EPT; ++j) {
    int e = base + j * 256;
    if (e < NE) {
      int r = erow[e];
      int c = ecol[e];
      vv[j] = eval[e];
      bk[j] = r >> BROW_BITS;
      key[j] = ((r & (BROWS - 1)) << 18) | c;
      rank[j] = atomicAdd(&lcnt[bk[j]], 1);
    } else {
      bk[j] = -1;
    }
  }
  __syncthreads();
  for (int i = threadIdx.x; i < NBK; i += 256) {
    int c = lcnt[i];
    lbase[i] = c ? atomicAdd(&gfill[i], c) : 0;
  }
  __syncthreads();
#pragma unroll
  for (int j = 0; j < SC_EPT; ++j) {
    if (bk[j] >= 0) {
      int p = bstart[bk[j]] + lbase[bk[j]] + rank[j];
      bkey[p] = key[j];
      bval[p] = vv[j];
    }
  }
}

// ================= Phase D: per-bucket CSR finalize + rp, (col,val) interleaved =================
__global__ __launch_bounds__(256) void csr_finalize(
    const int* __restrict__ bstart, const int* __restrict__ bkey,
    const float* __restrict__ bval, int* __restrict__ rp,
    int2* __restrict__ cv) {
  __shared__ int rcnt[BROWS];
  __shared__ int rex[BROWS];
  __shared__ int ss[BROWS];
  int b = blockIdx.x;
  int s0 = bstart[b], s1 = bstart[b + 1];
  int tid = threadIdx.x;
  if (tid < BROWS) rcnt[tid] = 0;
  __syncthreads();
  for (int j = s0 + tid; j < s1; j += 256) atomicAdd(&rcnt[bkey[j] >> 18], 1);
  __syncthreads();
  int v = (tid < BROWS) ? rcnt[tid] : 0;
  if (tid < BROWS) ss[tid] = v;
  __syncthreads();
  for (int off = 1; off < BROWS; off <<= 1) {
    int t = 0;
    if (tid < BROWS && tid >= off) t = ss[tid - off];
    __syncthreads();
    if (tid < BROWS) ss[tid] += t;
    __syncthreads();
  }
  if (tid < BROWS) {
    rex[tid] = ss[tid] - v;  // exclusive within bucket
    int row = b * BROWS + tid;
    if (row < NN) rp[row] = s0 + rex[tid];
    rcnt[tid] = 0;
  }
  __syncthreads();
  for (int j = s0 + tid; j < s1; j += 256) {
    int k = bkey[j];
    int r = k >> 18;
    int c = k & 0x3FFFF;
    int rk = atomicAdd(&rcnt[r], 1);
    int p = s0 + rex[r] + rk;
    cv[p] = make_int2(c, __float_as_int(bval[j]));
  }
}

// ================= fusion GEMM: [NI x 448] @ W^T + bias + leaky =================
__global__ __launch_bounds__(256) void fusion_kernel(
    const float* __restrict__ id_emb, const float* __restrict__ content,
    const float* __restrict__ W, const float* __restrict__ bias,
    float* __restrict__ ego) {
  __shared__ float As[16][68];
  __shared__ float Ws[16][68];
  int tid = threadIdx.x;
  int tx = tid & 15;
  int ty = tid >> 4;
  int itemBase = blockIdx.x * 64;
  float acc[4][4] = {};

  int it = tid >> 2;
  int kq = (tid & 3) * 4;

  for (int kb = 0; kb < KDIM; kb += 16) {
    int k = kb + kq;
    int item = itemBase + it;
    int itemc = item < NI ? item : NI - 1;
    float4 a;
    if (k < 64)
      a = *(const float4*)&id_emb[(size_t)itemc * 64 + k];
    else
      a = *(const float4*)&content[(size_t)itemc * 384 + (k - 64)];
    As[kq + 0][it] = a.x; As[kq + 1][it] = a.y; As[kq + 2][it] = a.z; As[kq + 3][it] = a.w;
    float4 w = *(const float4*)&W[(size_t)it * KDIM + k];
    Ws[kq + 0][it] = w.x; Ws[kq + 1][it] = w.y; Ws[kq + 2][it] = w.z; Ws[kq + 3][it] = w.w;
    __syncthreads();
#pragma unroll
    for (int kk = 0; kk < 16; ++kk) {
      float4 af = *(float4*)&As[kk][ty * 4];
      float4 wf = *(float4*)&Ws[kk][tx * 4];
      float av[4] = {af.x, af.y, af.z, af.w};
      float wv[4] = {wf.x, wf.y, wf.z, wf.w};
#pragma unroll
      for (int m = 0; m < 4; ++m)
#pragma unroll
        for (int n = 0; n < 4; ++n) acc[m][n] += av[m] * wv[n];
    }
    __syncthreads();
  }

  int d0 = tx * 4;
  float4 bb = *(const float4*)&bias[d0];
  float bv[4] = {bb.x, bb.y, bb.z, bb.w};
#pragma unroll
  for (int m = 0; m < 4; ++m) {
    int item = itemBase + ty * 4 + m;
    if (item >= NI) continue;
    float4 o;
    float t;
    t = acc[m][0] + bv[0]; o.x = t >= 0.f ? t : 0.01f * t;
    t = acc[m][1] + bv[1]; o.y = t >= 0.f ? t : 0.01f * t;
    t = acc[m][2] + bv[2]; o.z = t >= 0.f ? t : 0.01f * t;
    t = acc[m][3] + bv[3]; o.w = t >= 0.f ? t : 0.01f * t;
    *(float4*)&ego[(size_t)(NU + item) * 64 + d0] = o;
  }
}

// ================= fp32 -> fp16 convert =================
__global__ __launch_bounds__(256) void f2h_kernel(const float* __restrict__ x,
                                                  __half* __restrict__ y, int n) {
  int idx = (blockIdx.x * 256 + threadIdx.x) * 4;
  if (idx < n) {
    float4 f = *(const float4*)&x[idx];
    __half2 h0 = __floats2half2_rn(f.x, f.y);
    __half2 h1 = __floats2half2_rn(f.z, f.w);
    *(__half2*)&y[idx] = h0;
    *(__half2*)&y[idx + 2] = h1;
  }
}

// ================= SpMM: one wave per row, fp16 gather, 8-way MLP =================
template <bool FINAL>
__global__ __launch_bounds__(256) void spmm_kernel(
    const int* __restrict__ rp, const int2* __restrict__ cv,
    const __half* __restrict__ x, __half* __restrict__ y,
    float* __restrict__ acc) {
  int wid = blockIdx.x * 4 + (threadIdx.x >> 6);
  int lane = threadIdx.x & 63;
  if (wid >= NN) return;
  int beg = rp[wid], end = rp[wid + 1];
  float s0 = 0.f, s1 = 0.f, s2 = 0.f, s3 = 0.f;
  float s4 = 0.f, s5 = 0.f, s6 = 0.f, s7 = 0.f;
  for (int j0 = beg; j0 < end; j0 += 64) {
    int jj = j0 + lane;
    int c = 0;
    float v = 0.f;
    if (jj < end) {
      int2 p = cv[jj];
      c = p.x;
      v = __int_as_float(p.y);
    }
    int cnt = min(64, end - j0);
    int i = 0;
    for (; i + 8 <= cnt; i += 8) {
      int c0 = __shfl(c, i + 0), c1 = __shfl(c, i + 1);
      int c2 = __shfl(c, i + 2), c3 = __shfl(c, i + 3);
      int c4 = __shfl(c, i + 4), c5 = __shfl(c, i + 5);
      int c6 = __shfl(c, i + 6), c7 = __shfl(c, i + 7);
      float v0 = __shfl(v, i + 0), v1 = __shfl(v, i + 1);
      float v2 = __shfl(v, i + 2), v3 = __shfl(v, i + 3);
      float v4 = __shfl(v, i + 4), v5 = __shfl(v, i + 5);
      float v6 = __shfl(v, i + 6), v7 = __shfl(v, i + 7);
      // 8 independent 128B row gathers in flight before any dependent FMA
      float x0 = __half2float(x[(c0 << 6) | lane]);
      float x1 = __half2float(x[(c1 << 6) | lane]);
      float x2 = __half2float(x[(c2 << 6) | lane]);
      float x3 = __half2float(x[(c3 << 6) | lane]);
      float x4 = __half2float(x[(c4 << 6) | lane]);
      float x5 = __half2float(x[(c5 << 6) | lane]);
      float x6 = __half2float(x[(c6 << 6) | lane]);
      float x7 = __half2float(x[(c7 << 6) | lane]);
      s0 += v0 * x0; s1 += v1 * x1; s2 += v2 * x2; s3 += v3 * x3;
      s4 += v4 * x4; s5 += v5 * x5; s6 += v6 * x6; s7 += v7 * x7;
    }
    for (; i < cnt; ++i) {
      int ci = __shfl(c, i);
      float vi = __shfl(v, i);
      s0 += vi * __half2float(x[(ci << 6) | lane]);
    }
  }
  float s = ((s0 + s1) + (s2 + s3)) + ((s4 + s5) + (s6 + s7));
  int o = (wid << 6) | lane;
  if (FINAL) {
    acc[o] = (acc[o] + s) * 0.25f;
  } else {
    y[o] = __float2half(s);
    acc[o] += s;
  }
}

extern "C" void kernel_launch(void* const* d_in, const int* in_sizes, int n_in,
                              void* d_out, int out_size, void* d_ws, size_t ws_size,
                              hipStream_t stream) {
  const int*   edge_row = (const int*)d_in[0];
  const int*   edge_col = (const int*)d_in[1];
  const float* edge_val = (const float*)d_in[2];
  const float* user_emb = (const float*)d_in[3];
  const float* item_id  = (const float*)d_in[4];
  const float* brand    = (const float*)d_in[5];
  const float* content  = (const float*)d_in[6];
  const float* W        = (const float*)d_in[7];
  const float* bias     = (const float*)d_in[8];
  float* out = (float*)d_out;

  char* ws = (char*)d_ws;
  size_t off = 0;
  auto alloc = [&](size_t bytes) -> void* {
    void* p = ws + off;
    off += (bytes + 255) & ~(size_t)255;
    return p;
  };
  const size_t halfBufBytes = (size_t)NN * 64 * 2;  // 19.33 MB
  const size_t slotBytes = halfBufBytes > (size_t)NE * 4 ? halfBufBytes : (size_t)NE * 4;

  float* ego0f = (float*)alloc((size_t)NN * 64 * 4);  // fp32 ego (acc seed)
  void*  slotA = alloc(slotBytes);   // bkey during sort, xh0 during spmm
  void*  slotB = alloc(slotBytes);   // bval during sort, xh1 during spmm
  int*   rp    = (int*)alloc((size_t)(NN + 1) * 4);
  int*   bcnt  = (int*)alloc((NBK + 1) * 4);
  int*   bstart= (int*)alloc((NBK + 1) * 4);
  int*   gfill = (int*)alloc((NBK + 1) * 4);
  int2*  cv    = (int2*)alloc((size_t)NE * 8);  // interleaved (col, val)
  if (off > ws_size) return;

  int*   bkey = (int*)slotA;
  float* bval = (float*)slotB;
  __half* xh0 = (__half*)slotA;
  __half* xh1 = (__half*)slotB;

  // --- build CSR via two-level counting sort ---
  hipMemsetAsync(bcnt, 0, (NBK + 1) * 4, stream);
  hipMemsetAsync(gfill, 0, (NBK + 1) * 4, stream);
  const int histBlocks = (NE + 256 * HIST_EPT - 1) / (256 * HIST_EPT);
  bucket_hist<<<histBlocks, 256, 0, stream>>>(edge_row, bcnt);
  bucket_scan<<<1, 256, 0, stream>>>(bcnt, bstart, rp);
  const int scBlocks = (NE + 256 * SC_EPT - 1) / (256 * SC_EPT);
  bucket_scatter<<<scBlocks, 256, 0, stream>>>(edge_row, edge_col, edge_val,
                                               bstart, gfill, bkey, bval);
  csr_finalize<<<NBK, 256, 0, stream>>>(bstart, bkey, bval, rp, cv);

  // --- assemble ego0f = [user_emb | fused_item | brand_emb] ---
  hipMemcpyAsync(ego0f, user_emb, (size_t)NU * 64 * 4, hipMemcpyDeviceToDevice, stream);
  hipMemcpyAsync(ego0f + (size_t)(NU + NI) * 64, brand, (size_t)NB * 64 * 4,
                 hipMemcpyDeviceToDevice, stream);
  fusion_kernel<<<(NI + 63) / 64, 256, 0, stream>>>(item_id, content, W, bias, ego0f);

  // acc seed (out = ego0f), half conversion AFTER csr_finalize frees slotA
  hipMemcpyAsync(out, ego0f, (size_t)NN * 64 * 4, hipMemcpyDeviceToDevice, stream);
  const int nEl = NN * 64;
  f2h_kernel<<<(nEl / 4 + 255) / 256, 256, 0, stream>>>(ego0f, xh0, nEl);

  // --- 3 propagation layers ---
  const int spmmGrid = (NN + 3) / 4;
  spmm_kernel<false><<<spmmGrid, 256, 0, stream>>>(rp, cv, xh0, xh1, out);
  spmm_kernel<false><<<spmmGrid, 256, 0, stream>>>(rp, cv, xh1, xh0, out);
  spmm_kernel<true><<<spmmGrid, 256, 0, stream>>>(rp, cv, xh0, xh1, out);

  // --- passthrough outputs ---
  hipMemcpyAsync(out + (size_t)NN * 64, user_emb, (size_t)NU * 64 * 4,
                 hipMemcpyDeviceToDevice, stream);
  hipMemcpyAsync(out + (size_t)NN * 64 + (size_t)NU * 64, item_id,
                 (size_t)NI * 64 * 4, hipMemcpyDeviceToDevice, stream);
}

// Round 4
// 806.637 us; speedup vs baseline: 2.0098x; 1.0914x over previous
//
#include <hip/hip_runtime.h>
#include <hip/hip_fp16.h>

#define NU 100000
#define NI 50000
#define NB 1000
#define NN 151000          // total nodes
#define NE 4800000
#define KDIM 448

#define BROW_BITS 9
#define BROWS 512                       // rows per bucket
#define NBK ((NN + BROWS - 1) / BROWS)  // 295 buckets

// ================= Phase A: bucket histogram (LDS-aggregated) =================
#define HIST_EPT 16
__global__ __launch_bounds__(256) void bucket_hist(const int* __restrict__ erow,
                                                   int* __restrict__ bcnt) {
  __shared__ int lh[NBK];
  for (int i = threadIdx.x; i < NBK; i += 256) lh[i] = 0;
  __syncthreads();
  int base = blockIdx.x * (256 * HIST_EPT) + threadIdx.x;
#pragma unroll
  for (int j = 0; j < HIST_EPT; ++j) {
    int e = base + j * 256;
    if (e < NE) atomicAdd(&lh[erow[e] >> BROW_BITS], 1);
  }
  __syncthreads();
  for (int i = threadIdx.x; i < NBK; i += 256) {
    int c = lh[i];
    if (c) atomicAdd(&bcnt[i], c);
  }
}

// ================= Phase B: scan 295 bucket counts (single block) =================
__global__ __launch_bounds__(256) void bucket_scan(const int* __restrict__ bcnt,
                                                   int* __restrict__ bstart,
                                                   int* __restrict__ rp) {
  __shared__ int sh[256];
  int tid = threadIdx.x;
  int v[2];
  int s = 0;
#pragma unroll
  for (int j = 0; j < 2; ++j) {
    int i = tid * 2 + j;
    v[j] = (i < NBK) ? bcnt[i] : 0;
    s += v[j];
  }
  sh[tid] = s;
  __syncthreads();
  for (int off = 1; off < 256; off <<= 1) {
    int t = (tid >= off) ? sh[tid - off] : 0;
    __syncthreads();
    sh[tid] += t;
    __syncthreads();
  }
  int run = sh[tid] - s;  // exclusive
#pragma unroll
  for (int j = 0; j < 2; ++j) {
    int i = tid * 2 + j;
    if (i < NBK) bstart[i] = run;
    run += v[j];
  }
  if (tid == 255) {
    bstart[NBK] = NE;
    rp[NN] = NE;
  }
}

// ================= Phase C: scatter edges into bucket order =================
// key packs (row&511)<<18 | col  (col < 151000 < 2^18, key < 2^27)
#define SC_EPT 32
__global__ __launch_bounds__(256) void bucket_scatter(
    const int* __restrict__ erow, const int* __restrict__ ecol,
    const float* __restrict__ eval, const int* __restrict__ bstart,
    int* __restrict__ gfill, int2* __restrict__ cvtmp) {
  __shared__ int lcnt[NBK];
  __shared__ int lbase[NBK];
  __shared__ unsigned short lrank[256 * SC_EPT];  // 16 KB
  for (int i = threadIdx.x; i < NBK; i += 256) lcnt[i] = 0;
  __syncthreads();
  int base = blockIdx.x * (256 * SC_EPT) + threadIdx.x;
  // phase 1: per-(block,bucket) ranks
#pragma unroll 4
  for (int j = 0; j < SC_EPT; ++j) {
    int e = base + j * 256;
    if (e < NE) {
      int bk = erow[e] >> BROW_BITS;
      lrank[j * 256 + threadIdx.x] = (unsigned short)atomicAdd(&lcnt[bk], 1);
    }
  }
  __syncthreads();
  // reserve global ranges (one atomic per non-empty bucket per block)
  for (int i = threadIdx.x; i < NBK; i += 256) {
    int c = lcnt[i];
    lbase[i] = c ? atomicAdd(&gfill[i], c) : 0;
  }
  __syncthreads();
  // phase 2: packed 8B writes; ~28 consecutive edges per bucket per block
#pragma unroll 4
  for (int j = 0; j < SC_EPT; ++j) {
    int e = base + j * 256;
    if (e < NE) {
      int r = erow[e];
      int c = ecol[e];
      float v = eval[e];
      int bk = r >> BROW_BITS;
      int key = ((r & (BROWS - 1)) << 18) | c;
      int p = bstart[bk] + lbase[bk] + lrank[j * 256 + threadIdx.x];
      cvtmp[p] = make_int2(key, __float_as_int(v));
    }
  }
}

// ================= Phase D: per-bucket CSR finalize + rp =================
__global__ __launch_bounds__(256) void csr_finalize(
    const int* __restrict__ bstart, const int2* __restrict__ cvtmp,
    int* __restrict__ rp, int2* __restrict__ cv) {
  __shared__ int rcnt[BROWS];
  __shared__ int rex[BROWS];
  __shared__ int ssh[256];
  int b = blockIdx.x;
  int s0 = bstart[b], s1 = bstart[b + 1];
  int tid = threadIdx.x;
  rcnt[tid] = 0;
  rcnt[tid + 256] = 0;
  __syncthreads();
  for (int j = s0 + tid; j < s1; j += 256) atomicAdd(&rcnt[cvtmp[j].x >> 18], 1);
  __syncthreads();
  int v0 = rcnt[2 * tid], v1 = rcnt[2 * tid + 1];
  int tsum = v0 + v1;
  ssh[tid] = tsum;
  __syncthreads();
  for (int off = 1; off < 256; off <<= 1) {
    int t = (tid >= off) ? ssh[tid - off] : 0;
    __syncthreads();
    ssh[tid] += t;
    __syncthreads();
  }
  int excl = ssh[tid] - tsum;
  rex[2 * tid] = excl;
  rex[2 * tid + 1] = excl + v0;
  int row = b * BROWS + 2 * tid;
  if (row < NN) rp[row] = s0 + excl;
  if (row + 1 < NN) rp[row + 1] = s0 + excl + v0;
  rcnt[2 * tid] = 0;
  rcnt[2 * tid + 1] = 0;
  __syncthreads();
  for (int j = s0 + tid; j < s1; j += 256) {
    int2 kv = cvtmp[j];
    int r = kv.x >> 18;
    int c = kv.x & 0x3FFFF;
    int rk = atomicAdd(&rcnt[r], 1);
    cv[s0 + rex[r] + rk] = make_int2(c, kv.y);
  }
}

// ================= fusion GEMM: [NI x 448] @ W^T + bias + leaky =================
__global__ __launch_bounds__(256) void fusion_kernel(
    const float* __restrict__ id_emb, const float* __restrict__ content,
    const float* __restrict__ W, const float* __restrict__ bias,
    float* __restrict__ ego) {
  __shared__ float As[16][68];
  __shared__ float Ws[16][68];
  int tid = threadIdx.x;
  int tx = tid & 15;
  int ty = tid >> 4;
  int itemBase = blockIdx.x * 64;
  float acc[4][4] = {};

  int it = tid >> 2;
  int kq = (tid & 3) * 4;

  for (int kb = 0; kb < KDIM; kb += 16) {
    int k = kb + kq;
    int item = itemBase + it;
    int itemc = item < NI ? item : NI - 1;
    float4 a;
    if (k < 64)
      a = *(const float4*)&id_emb[(size_t)itemc * 64 + k];
    else
      a = *(const float4*)&content[(size_t)itemc * 384 + (k - 64)];
    As[kq + 0][it] = a.x; As[kq + 1][it] = a.y; As[kq + 2][it] = a.z; As[kq + 3][it] = a.w;
    float4 w = *(const float4*)&W[(size_t)it * KDIM + k];
    Ws[kq + 0][it] = w.x; Ws[kq + 1][it] = w.y; Ws[kq + 2][it] = w.z; Ws[kq + 3][it] = w.w;
    __syncthreads();
#pragma unroll
    for (int kk = 0; kk < 16; ++kk) {
      float4 af = *(float4*)&As[kk][ty * 4];
      float4 wf = *(float4*)&Ws[kk][tx * 4];
      float av[4] = {af.x, af.y, af.z, af.w};
      float wv[4] = {wf.x, wf.y, wf.z, wf.w};
#pragma unroll
      for (int m = 0; m < 4; ++m)
#pragma unroll
        for (int n = 0; n < 4; ++n) acc[m][n] += av[m] * wv[n];
    }
    __syncthreads();
  }

  int d0 = tx * 4;
  float4 bb = *(const float4*)&bias[d0];
  float bv[4] = {bb.x, bb.y, bb.z, bb.w};
#pragma unroll
  for (int m = 0; m < 4; ++m) {
    int item = itemBase + ty * 4 + m;
    if (item >= NI) continue;
    float4 o;
    float t;
    t = acc[m][0] + bv[0]; o.x = t >= 0.f ? t : 0.01f * t;
    t = acc[m][1] + bv[1]; o.y = t >= 0.f ? t : 0.01f * t;
    t = acc[m][2] + bv[2]; o.z = t >= 0.f ? t : 0.01f * t;
    t = acc[m][3] + bv[3]; o.w = t >= 0.f ? t : 0.01f * t;
    *(float4*)&ego[(size_t)(NU + item) * 64 + d0] = o;
  }
}

// ================= fp32 -> fp16 convert, also seeds acc (out) =================
__global__ __launch_bounds__(256) void f2h_kernel(const float* __restrict__ x,
                                                  __half* __restrict__ y,
                                                  float* __restrict__ out, int n) {
  int idx = (blockIdx.x * 256 + threadIdx.x) * 4;
  if (idx < n) {
    float4 f = *(const float4*)&x[idx];
    __half2 h0 = __floats2half2_rn(f.x, f.y);
    __half2 h1 = __floats2half2_rn(f.z, f.w);
    *(__half2*)&y[idx] = h0;
    *(__half2*)&y[idx + 2] = h1;
    *(float4*)&out[idx] = f;
  }
}

// ================= SpMM: one wave per row, fp16 gather, 8-way MLP =================
template <bool FINAL>
__global__ __launch_bounds__(256) void spmm_kernel(
    const int* __restrict__ rp, const int2* __restrict__ cv,
    const __half* __restrict__ x, __half* __restrict__ y,
    float* __restrict__ acc) {
  int wid = blockIdx.x * 4 + (threadIdx.x >> 6);
  int lane = threadIdx.x & 63;
  if (wid >= NN) return;
  int beg = rp[wid], end = rp[wid + 1];
  float s0 = 0.f, s1 = 0.f, s2 = 0.f, s3 = 0.f;
  float s4 = 0.f, s5 = 0.f, s6 = 0.f, s7 = 0.f;
  for (int j0 = beg; j0 < end; j0 += 64) {
    int jj = j0 + lane;
    int c = 0;
    float v = 0.f;
    if (jj < end) {
      int2 p = cv[jj];
      c = p.x;
      v = __int_as_float(p.y);
    }
    int cnt = min(64, end - j0);
    int i = 0;
    for (; i + 8 <= cnt; i += 8) {
      int c0 = __shfl(c, i + 0), c1 = __shfl(c, i + 1);
      int c2 = __shfl(c, i + 2), c3 = __shfl(c, i + 3);
      int c4 = __shfl(c, i + 4), c5 = __shfl(c, i + 5);
      int c6 = __shfl(c, i + 6), c7 = __shfl(c, i + 7);
      float v0 = __shfl(v, i + 0), v1 = __shfl(v, i + 1);
      float v2 = __shfl(v, i + 2), v3 = __shfl(v, i + 3);
      float v4 = __shfl(v, i + 4), v5 = __shfl(v, i + 5);
      float v6 = __shfl(v, i + 6), v7 = __shfl(v, i + 7);
      float x0 = __half2float(x[(c0 << 6) | lane]);
      float x1 = __half2float(x[(c1 << 6) | lane]);
      float x2 = __half2float(x[(c2 << 6) | lane]);
      float x3 = __half2float(x[(c3 << 6) | lane]);
      float x4 = __half2float(x[(c4 << 6) | lane]);
      float x5 = __half2float(x[(c5 << 6) | lane]);
      float x6 = __half2float(x[(c6 << 6) | lane]);
      float x7 = __half2float(x[(c7 << 6) | lane]);
      s0 += v0 * x0; s1 += v1 * x1; s2 += v2 * x2; s3 += v3 * x3;
      s4 += v4 * x4; s5 += v5 * x5; s6 += v6 * x6; s7 += v7 * x7;
    }
    for (; i < cnt; ++i) {
      int ci = __shfl(c, i);
      float vi = __shfl(v, i);
      s0 += vi * __half2float(x[(ci << 6) | lane]);
    }
  }
  float s = ((s0 + s1) + (s2 + s3)) + ((s4 + s5) + (s6 + s7));
  int o = (wid << 6) | lane;
  if (FINAL) {
    acc[o] = (acc[o] + s) * 0.25f;
  } else {
    y[o] = __float2half(s);
    acc[o] += s;
  }
}

extern "C" void kernel_launch(void* const* d_in, const int* in_sizes, int n_in,
                              void* d_out, int out_size, void* d_ws, size_t ws_size,
                              hipStream_t stream) {
  const int*   edge_row = (const int*)d_in[0];
  const int*   edge_col = (const int*)d_in[1];
  const float* edge_val = (const float*)d_in[2];
  const float* user_emb = (const float*)d_in[3];
  const float* item_id  = (const float*)d_in[4];
  const float* brand    = (const float*)d_in[5];
  const float* content  = (const float*)d_in[6];
  const float* W        = (const float*)d_in[7];
  const float* bias     = (const float*)d_in[8];
  float* out = (float*)d_out;

  char* ws = (char*)d_ws;
  size_t off = 0;
  auto alloc = [&](size_t bytes) -> void* {
    void* p = ws + off;
    off += (bytes + 255) & ~(size_t)255;
    return p;
  };
  const size_t halfBufBytes = (size_t)NN * 64 * 2;  // 19.33 MB (multiple of 256)
  const size_t slabBytes = 2 * halfBufBytes > (size_t)NE * 8 ? 2 * halfBufBytes
                                                             : (size_t)NE * 8;

  float* ego0f = (float*)alloc((size_t)NN * 64 * 4);  // fp32 ego (acc seed)
  char*  slab  = (char*)alloc(slabBytes);  // cvtmp during sort; xh0+xh1 during spmm
  int*   rp    = (int*)alloc((size_t)(NN + 1) * 4);
  int*   bcnt  = (int*)alloc((NBK + 1) * 4);
  int*   bstart= (int*)alloc((NBK + 1) * 4);
  int*   gfill = (int*)alloc((NBK + 1) * 4);
  int2*  cv    = (int2*)alloc((size_t)NE * 8);  // final CSR (col, val) interleaved
  if (off > ws_size) return;

  int2*   cvtmp = (int2*)slab;
  __half* xh0   = (__half*)slab;
  __half* xh1   = (__half*)(slab + halfBufBytes);

  // --- build CSR via two-level counting sort ---
  hipMemsetAsync(bcnt, 0, (NBK + 1) * 4, stream);
  hipMemsetAsync(gfill, 0, (NBK + 1) * 4, stream);
  const int histBlocks = (NE + 256 * HIST_EPT - 1) / (256 * HIST_EPT);
  bucket_hist<<<histBlocks, 256, 0, stream>>>(edge_row, bcnt);
  bucket_scan<<<1, 256, 0, stream>>>(bcnt, bstart, rp);
  const int scBlocks = (NE + 256 * SC_EPT - 1) / (256 * SC_EPT);
  bucket_scatter<<<scBlocks, 256, 0, stream>>>(edge_row, edge_col, edge_val,
                                               bstart, gfill, cvtmp);
  csr_finalize<<<NBK, 256, 0, stream>>>(bstart, cvtmp, rp, cv);

  // --- assemble ego0f = [user_emb | fused_item | brand_emb] ---
  hipMemcpyAsync(ego0f, user_emb, (size_t)NU * 64 * 4, hipMemcpyDeviceToDevice, stream);
  hipMemcpyAsync(ego0f + (size_t)(NU + NI) * 64, brand, (size_t)NB * 64 * 4,
                 hipMemcpyDeviceToDevice, stream);
  fusion_kernel<<<(NI + 63) / 64, 256, 0, stream>>>(item_id, content, W, bias, ego0f);

  // fp16 conversion + acc seed (after csr_finalize frees slab)
  const int nEl = NN * 64;
  f2h_kernel<<<(nEl / 4 + 255) / 256, 256, 0, stream>>>(ego0f, xh0, out, nEl);

  // --- 3 propagation layers ---
  const int spmmGrid = (NN + 3) / 4;
  spmm_kernel<false><<<spmmGrid, 256, 0, stream>>>(rp, cv, xh0, xh1, out);
  spmm_kernel<false><<<spmmGrid, 256, 0, stream>>>(rp, cv, xh1, xh0, out);
  spmm_kernel<true><<<spmmGrid, 256, 0, stream>>>(rp, cv, xh0, xh1, out);

  // --- passthrough outputs ---
  hipMemcpyAsync(out + (size_t)NN * 64, user_emb, (size_t)NU * 64 * 4,
                 hipMemcpyDeviceToDevice, stream);
  hipMemcpyAsync(out + (size_t)NN * 64 + (size_t)NU * 64, item_id,
                 (size_t)NI * 64 * 4, hipMemcpyDeviceToDevice, stream);
}